// Round 12
// baseline (509.188 us; speedup 1.0000x reference)
//
#include <hip/hip_runtime.h>
#include <stdint.h>

typedef int   i32x4  __attribute__((ext_vector_type(4)));
typedef int   i32x16 __attribute__((ext_vector_type(16)));
typedef float f32x4  __attribute__((ext_vector_type(4)));

#define AS1 __attribute__((address_space(1)))
#define AS3 __attribute__((address_space(3)))
#define G2L16(gp, lp) __builtin_amdgcn_global_load_lds((const AS1 void*)(gp), (AS3 void*)(lp), 16, 0, 0)

// ---------------- symmetric int8 row quantization (at BW floor) ----------------
template<int COLS>
__global__ __launch_bounds__(256)
void quant_rows_k(const float* __restrict__ src, int8_t* __restrict__ q,
                  float* __restrict__ scale)
{
    constexpr int PER = COLS / 256;   // 16
    static_assert(PER == 16, "pack assumes 16 elems/thread");
    const int row = blockIdx.x;
    const int t   = threadIdx.x;
    const float* s = src + (size_t)row * COLS + (size_t)t * PER;

    float v[PER];
    #pragma unroll
    for (int i = 0; i < PER; i += 4) {
        f32x4 x4 = *reinterpret_cast<const f32x4*>(s + i);
        v[i+0] = x4[0]; v[i+1] = x4[1]; v[i+2] = x4[2]; v[i+3] = x4[3];
    }
    float amax = 0.0f;
    #pragma unroll
    for (int i = 0; i < PER; ++i) amax = fmaxf(amax, fabsf(v[i]));

    #pragma unroll
    for (int off = 32; off > 0; off >>= 1)
        amax = fmaxf(amax, __shfl_xor(amax, off, 64));

    __shared__ float red[4];
    if ((t & 63) == 0) red[t >> 6] = amax;
    __syncthreads();
    amax = fmaxf(fmaxf(red[0], red[1]), fmaxf(red[2], red[3]));

    const float sc = fmaxf(amax, 1e-8f) / 127.0f;
    if (t == 0) scale[row] = sc;

    union { i32x4 v4; int8_t b[16]; } pk;
    #pragma unroll
    for (int i = 0; i < PER; ++i) {
        float r = rintf(v[i] / sc);
        r = fminf(127.0f, fmaxf(-127.0f, r));
        pk.b[i] = (int8_t)r;
    }
    *reinterpret_cast<i32x4*>(q + (size_t)row * COLS + (size_t)t * PER) = pk.v4;
}

// ---------------- int8 GEMM, 256x256 tile, mfma_i32_32x32x32_i8, fragment-ordered LDS ----------
// 512 threads = 8 waves (2M x 4N), wave tile 128x64 = 4x2 tiles of 32x32, BK=128 B (4 k-slices
// of K=32). LDS is stored in FRAGMENT ORDER: slot = fragIdx*1024 + lane*16, so every
// ds_read_b128 is lane-linear (optimal banks, no XOR). global_load_lds dest stays linear;
// the SOURCE address encodes the fragment permutation (rule: linear dest + permuted source).
// A frag layout (extrapolated from verified 16x16x64): row = lane&31, k = (lane>>5)*16 + j.
// C/D (guide-verified, dtype-independent): col = lane&31, row = (r&3) + 8*(r>>2) + 4*(lane>>5).
// Frag units (1 KB each, 32 per side per buffer): A unit idx = (ksl>>1)*16 + (mtile>>2)*8
// + (mtile&3)*2 + (ksl&1); staged as 4 calls x 8 KB: call c = {mhalf=c&1, kpair=c>>1}.
// Phases: P0 = ks{0,1} x m{0,1}, P1 = ks{0,1} x m{2,3}, P2 = ks{2,3} x m{0,1}, P3 = ks{2,3} x m{2,3};
// B frags live 2 phases. Stage (tile t+1 during t): P0:{Bc0,Bc1} P1:{Bc2,Bc3} P2:{Ac0,Ac1} P3:{Ac2,Ac3}.
// Waits (r2's proven ledger): end-P1 vmcnt(4) drains prev s4={Ac2,Ac3} before P2 reads ks23;
// end-P3 vmcnt(2) drains next tile's {Bc0..3,Ac0,Ac1}, keeps {Ac2,Ac3}. Never 0 in steady state.
#define BM 256
#define BN 256
#define BKB 128

__device__ __forceinline__ i32x16 mfma32(i32x4 a, i32x4 b, i32x16 c) {
    return __builtin_amdgcn_mfma_i32_32x32x32_i8(a, b, c, 0, 0, 0);
}
__device__ __forceinline__ i32x4 ldsld(const int8_t* p) {
    return *reinterpret_cast<const i32x4*>(p);
}
#define FENCE asm volatile("" ::: "memory")
#define BAR   do { FENCE; __builtin_amdgcn_s_barrier(); FENCE; } while (0)
#define LGKM0 asm volatile("s_waitcnt lgkmcnt(0)" ::: "memory")
#define SCHB  __builtin_amdgcn_sched_barrier(0)

template<bool ST>
__device__ __forceinline__ void tile_fn(
    const int8_t* __restrict__ aP, const int8_t* __restrict__ bP,  // frag bases (cur buf, incl wave+lane)
    i32x16 (&acc)[4][2],
    const int8_t* __restrict__ gA, const int8_t* __restrict__ gB,  // per-thread stage src (next tile)
    int8_t* lAn, int8_t* lBn,                                      // next-buf LDS bases
    size_t r128, int t16)
{
    // ================= P0: ks{0,1} x m{0,1} =================
    i32x4 a00 = ldsld(aP + 0);      // (m0,ks0)
    i32x4 a01 = ldsld(aP + 1024);   // (m0,ks1)
    i32x4 a10 = ldsld(aP + 2048);   // (m1,ks0)
    i32x4 a11 = ldsld(aP + 3072);   // (m1,ks1)
    i32x4 b00 = ldsld(bP + 0);      // (n0,ks0)
    i32x4 b01 = ldsld(bP + 1024);   // (n0,ks1)
    i32x4 b10 = ldsld(bP + 2048);   // (n1,ks0)
    i32x4 b11 = ldsld(bP + 3072);   // (n1,ks1)
    if (ST) {                        // stage s1 = {B call0, B call1}
        G2L16(gB,        lBn + t16);
        G2L16(gB + r128, lBn + 8192 + t16);
    }
    BAR; LGKM0; SCHB;
    __builtin_amdgcn_s_setprio(1);
    acc[0][0] = mfma32(a00, b00, acc[0][0]);
    acc[1][0] = mfma32(a10, b00, acc[1][0]);
    acc[0][1] = mfma32(a00, b10, acc[0][1]);
    acc[1][1] = mfma32(a10, b10, acc[1][1]);
    acc[0][0] = mfma32(a01, b01, acc[0][0]);
    acc[1][0] = mfma32(a11, b01, acc[1][0]);
    acc[0][1] = mfma32(a01, b11, acc[0][1]);
    acc[1][1] = mfma32(a11, b11, acc[1][1]);
    __builtin_amdgcn_s_setprio(0);
    BAR;
    // ================= P1: ks{0,1} x m{2,3} (B frags reused) =================
    i32x4 a20 = ldsld(aP + 4096);   // (m2,ks0)
    i32x4 a21 = ldsld(aP + 5120);   // (m2,ks1)
    i32x4 a30 = ldsld(aP + 6144);   // (m3,ks0)
    i32x4 a31 = ldsld(aP + 7168);   // (m3,ks1)
    if (ST) {                        // stage s2 = {B call2, B call3}
        G2L16(gB + 64,        lBn + 16384 + t16);
        G2L16(gB + r128 + 64, lBn + 24576 + t16);
    }
    BAR; LGKM0; SCHB;
    __builtin_amdgcn_s_setprio(1);
    acc[2][0] = mfma32(a20, b00, acc[2][0]);
    acc[3][0] = mfma32(a30, b00, acc[3][0]);
    acc[2][1] = mfma32(a20, b10, acc[2][1]);
    acc[3][1] = mfma32(a30, b10, acc[3][1]);
    acc[2][0] = mfma32(a21, b01, acc[2][0]);
    acc[3][0] = mfma32(a31, b01, acc[3][0]);
    acc[2][1] = mfma32(a21, b11, acc[2][1]);
    acc[3][1] = mfma32(a31, b11, acc[3][1]);
    __builtin_amdgcn_s_setprio(0);
    // drain prev tile's s4 = {A call2, call3} of CURRENT buf (all waves, then barrier)
    if (ST) asm volatile("s_waitcnt vmcnt(4)" ::: "memory");
    else    asm volatile("s_waitcnt vmcnt(0)" ::: "memory");
    BAR;
    // ================= P2: ks{2,3} x m{0,1} =================
    i32x4 c00 = ldsld(aP + 16384);  // (m0,ks2)
    i32x4 c01 = ldsld(aP + 17408);  // (m0,ks3)
    i32x4 c10 = ldsld(aP + 18432);  // (m1,ks2)
    i32x4 c11 = ldsld(aP + 19456);  // (m1,ks3)
    i32x4 d00 = ldsld(bP + 16384);  // (n0,ks2)
    i32x4 d01 = ldsld(bP + 17408);  // (n0,ks3)
    i32x4 d10 = ldsld(bP + 18432);  // (n1,ks2)
    i32x4 d11 = ldsld(bP + 19456);  // (n1,ks3)
    if (ST) {                        // stage s3 = {A call0, A call1}
        G2L16(gA,        lAn + t16);
        G2L16(gA + r128, lAn + 8192 + t16);
    }
    BAR; LGKM0; SCHB;
    __builtin_amdgcn_s_setprio(1);
    acc[0][0] = mfma32(c00, d00, acc[0][0]);
    acc[1][0] = mfma32(c10, d00, acc[1][0]);
    acc[0][1] = mfma32(c00, d10, acc[0][1]);
    acc[1][1] = mfma32(c10, d10, acc[1][1]);
    acc[0][0] = mfma32(c01, d01, acc[0][0]);
    acc[1][0] = mfma32(c11, d01, acc[1][0]);
    acc[0][1] = mfma32(c01, d11, acc[0][1]);
    acc[1][1] = mfma32(c11, d11, acc[1][1]);
    __builtin_amdgcn_s_setprio(0);
    BAR;
    // ================= P3: ks{2,3} x m{2,3} (d-frags reused) =================
    i32x4 e00 = ldsld(aP + 20480);  // (m2,ks2)
    i32x4 e01 = ldsld(aP + 21504);  // (m2,ks3)
    i32x4 e10 = ldsld(aP + 22528);  // (m3,ks2)
    i32x4 e11 = ldsld(aP + 23552);  // (m3,ks3)
    if (ST) {                        // stage s4 = {A call2, A call3}
        G2L16(gA + 64,        lAn + 16384 + t16);
        G2L16(gA + r128 + 64, lAn + 24576 + t16);
    }
    BAR; LGKM0; SCHB;
    __builtin_amdgcn_s_setprio(1);
    acc[2][0] = mfma32(e00, d00, acc[2][0]);
    acc[3][0] = mfma32(e10, d00, acc[3][0]);
    acc[2][1] = mfma32(e00, d10, acc[2][1]);
    acc[3][1] = mfma32(e10, d10, acc[3][1]);
    acc[2][0] = mfma32(e01, d01, acc[2][0]);
    acc[3][0] = mfma32(e11, d01, acc[3][0]);
    acc[2][1] = mfma32(e01, d11, acc[2][1]);
    acc[3][1] = mfma32(e11, d11, acc[3][1]);
    __builtin_amdgcn_s_setprio(0);
    if (ST) asm volatile("s_waitcnt vmcnt(2)" ::: "memory");  // drain s1-s3(next); keep s4(next)
    else    asm volatile("s_waitcnt vmcnt(0)" ::: "memory");
    BAR;
}

__global__ __launch_bounds__(512, 2)
void gemm_i8_k(const int8_t* __restrict__ A,    // [M][K]
               const int8_t* __restrict__ B,    // [N][K]
               const float*  __restrict__ sx,   // [M]
               const float*  __restrict__ sw,   // [N]
               const float*  __restrict__ bias, // [N]
               float* __restrict__ C,           // [M][N]
               int M, int N, int K)
{
    __shared__ int8_t lA[2][32768];   // 32 frag-units x 1KB per buffer
    __shared__ int8_t lB[2][32768];

    const int t    = threadIdx.x;
    const int lane = t & 63;
    const int wid  = t >> 6;
    const int wm   = wid >> 2;   // 0..1
    const int wn   = wid & 3;    // 0..3

    // bijective XCD swizzle (nwg = 1024, multiple of 8)
    const int nwg = (int)gridDim.x;
    const int bid = (int)blockIdx.x;
    const int swz = ((nwg & 7) == 0) ? ((bid & 7) * (nwg >> 3) + (bid >> 3)) : bid;
    const int nbn = N / BN;
    const int bm  = swz / nbn;
    const int bn  = swz % nbn;

    // fragment-read bases (lane-linear: base + const_offset, addr = ... + lane*16)
    const int8_t* aP0 = &lA[0][wm * 8192 + lane * 16];
    const int8_t* aP1 = &lA[1][wm * 8192 + lane * 16];
    const int8_t* bP0 = &lB[0][(wn >> 1) * 8192 + (wn & 1) * 4096 + lane * 16];
    const int8_t* bP1 = &lB[1][(wn >> 1) * 8192 + (wn & 1) * 4096 + lane * 16];

    // staging source (fragment-order permutation encoded in the GLOBAL address):
    // call c covers {mhalf=c&1 (+128 rows), kpair=c>>1 (+64 B)}; within a call,
    // thread t -> mtile&3 = t>>7, ksl&1 = (t>>6)&1, row-in-tile = t&31, khalf = (t>>5)&1.
    const int rS = ((t >> 7) * 32) + (t & 31);                  // 0..127
    const int kS = ((t >> 6) & 1) * 32 + ((t >> 5) & 1) * 16;   // 0..48
    const int t16 = t * 16;
    const int8_t* pA = A + (size_t)(bm * BM + rS) * K + kS;
    const int8_t* pB = B + (size_t)(bn * BN + rS) * K + kS;
    const size_t r128 = (size_t)128 * K;

    // prologue: stage K-tile 0 into buffer 0 in steady-state order s1,s2,s3,s4
    G2L16(pB,              &lB[0][0]     + t16);   // B c0
    G2L16(pB + r128,       &lB[0][8192]  + t16);   // B c1
    G2L16(pB + 64,         &lB[0][16384] + t16);   // B c2
    G2L16(pB + r128 + 64,  &lB[0][24576] + t16);   // B c3
    G2L16(pA,              &lA[0][0]     + t16);   // A c0
    G2L16(pA + r128,       &lA[0][8192]  + t16);   // A c1
    G2L16(pA + 64,         &lA[0][16384] + t16);   // A c2
    G2L16(pA + r128 + 64,  &lA[0][24576] + t16);   // A c3
    asm volatile("s_waitcnt vmcnt(2)" ::: "memory");   // s1-s3 resident; s4={Ac2,Ac3} in flight
    BAR;

    i32x16 acc[4][2] = {};

    const int NT = K / BKB;   // 32 (even)
    for (int tt = 0; tt + 2 < NT; tt += 2) {
        const size_t ko1 = (size_t)(tt + 1) * BKB;
        tile_fn<true>(aP0, bP0, acc, pA + ko1, pB + ko1, &lA[1][0], &lB[1][0], r128, t16);
        const size_t ko2 = (size_t)(tt + 2) * BKB;
        tile_fn<true>(aP1, bP1, acc, pA + ko2, pB + ko2, &lA[0][0], &lB[0][0], r128, t16);
    }
    {   // last two tiles: NT-2 (stages NT-1), then NT-1 (no stage)
        const size_t ko1 = (size_t)(NT - 1) * BKB;
        tile_fn<true >(aP0, bP0, acc, pA + ko1, pB + ko1, &lA[1][0], &lB[1][0], r128, t16);
        tile_fn<false>(aP1, bP1, acc, pA, pB, &lA[0][0], &lB[0][0], r128, t16);
    }

    // epilogue: dequant + bias; 32x32 C/D layout -> 128 B coalesced segments per half-wave
    const int hi   = lane >> 5;
    const int col0 = bn * BN + wn * 64 + (lane & 31);
    #pragma unroll
    for (int ni = 0; ni < 2; ++ni) {
        const int c = col0 + ni * 32;
        const float swc = sw[c];
        const float bc  = bias[c];
        #pragma unroll
        for (int mi = 0; mi < 4; ++mi) {
            const int rb = bm * BM + wm * 128 + mi * 32 + 4 * hi;
            #pragma unroll
            for (int r = 0; r < 16; ++r) {
                const int row = rb + (r & 3) + 8 * (r >> 2);
                C[(size_t)row * N + c] = (float)acc[mi][ni][r] * sx[row] * swc + bc;
            }
        }
    }
}

extern "C" void kernel_launch(void* const* d_in, const int* in_sizes, int n_in,
                              void* d_out, int out_size, void* d_ws, size_t ws_size,
                              hipStream_t stream) {
    const float* x    = (const float*)d_in[0];
    const float* w    = (const float*)d_in[1];
    const float* bias = (const float*)d_in[2];
    float* out = (float*)d_out;

    const int dout   = in_sizes[2];          // 16384
    const int din    = in_sizes[1] / dout;   // 4096
    const int tokens = in_sizes[0] / din;    // 4096

    char* ws = (char*)d_ws;
    float*  sx = (float*)ws;
    float*  sw = (float*)(ws + 16384);
    int8_t* xq = (int8_t*)(ws + 16384 + 65536);
    int8_t* wq = xq + (size_t)tokens * din;

    quant_rows_k<4096><<<tokens, 256, 0, stream>>>(x, xq, sx);
    quant_rows_k<4096><<<dout,   256, 0, stream>>>(w, wq, sw);

    const int grid = (tokens / BM) * (dout / BN);   // 16 * 64 = 1024
    gemm_i8_k<<<grid, 512, 0, stream>>>(xq, wq, sx, sw, bias, out, tokens, dout, din);
}

// Round 13
// 485.035 us; speedup vs baseline: 1.0498x; 1.0498x over previous
//
#include <hip/hip_runtime.h>
#include <stdint.h>

typedef int   i32x4  __attribute__((ext_vector_type(4)));
typedef int   i32x16 __attribute__((ext_vector_type(16)));
typedef float f32x4  __attribute__((ext_vector_type(4)));

#define AS1 __attribute__((address_space(1)))
#define AS3 __attribute__((address_space(3)))
#define G2L16(gp, lp) __builtin_amdgcn_global_load_lds((const AS1 void*)(gp), (AS3 void*)(lp), 16, 0, 0)

// ---------------- symmetric int8 row quantization (at BW floor) ----------------
template<int COLS>
__global__ __launch_bounds__(256)
void quant_rows_k(const float* __restrict__ src, int8_t* __restrict__ q,
                  float* __restrict__ scale)
{
    constexpr int PER = COLS / 256;   // 16
    static_assert(PER == 16, "pack assumes 16 elems/thread");
    const int row = blockIdx.x;
    const int t   = threadIdx.x;
    const float* s = src + (size_t)row * COLS + (size_t)t * PER;

    float v[PER];
    #pragma unroll
    for (int i = 0; i < PER; i += 4) {
        f32x4 x4 = *reinterpret_cast<const f32x4*>(s + i);
        v[i+0] = x4[0]; v[i+1] = x4[1]; v[i+2] = x4[2]; v[i+3] = x4[3];
    }
    float amax = 0.0f;
    #pragma unroll
    for (int i = 0; i < PER; ++i) amax = fmaxf(amax, fabsf(v[i]));

    #pragma unroll
    for (int off = 32; off > 0; off >>= 1)
        amax = fmaxf(amax, __shfl_xor(amax, off, 64));

    __shared__ float red[4];
    if ((t & 63) == 0) red[t >> 6] = amax;
    __syncthreads();
    amax = fmaxf(fmaxf(red[0], red[1]), fmaxf(red[2], red[3]));

    const float sc = fmaxf(amax, 1e-8f) / 127.0f;
    if (t == 0) scale[row] = sc;

    union { i32x4 v4; int8_t b[16]; } pk;
    #pragma unroll
    for (int i = 0; i < PER; ++i) {
        float r = rintf(v[i] / sc);
        r = fminf(127.0f, fmaxf(-127.0f, r));
        pk.b[i] = (int8_t)r;
    }
    *reinterpret_cast<i32x4*>(q + (size_t)row * COLS + (size_t)t * PER) = pk.v4;
}

// ---------------- int8 GEMM, 256x256 tile, mfma_i32_32x32x32_i8 on r2's proven skeleton ------
// 512 threads = 8 waves (2M x 4N), wave tile 128x64 = 4m x 2n tiles of 32x32, BK = 128 B
// (4 k-slices of K=32). LDS: row-major [256][128] per side, XOR chunk swizzle
// (chunk' = chunk ^ (row&7)), STAGING IDENTICAL to r2 (coalesced 128B-per-row source,
// linear G2L dest). Fragment read (validated on HW in r11): lane l reads
// row = tile*32 + (l&31), source chunk = 2*ks + (l>>5) -> LDS chunk (2ks+hi)^(l&7).
// Phases: P0 = ks{0,1} x m{0,1}, P1 = ks{2,3} x m{0,1}, P2 = ks{0,1} x m{2,3},
// P3 = ks{2,3} x m{2,3}; 8 MFMA/phase; B frags live 2 phases (P0->P2, P1->P3).
// Stage (tile t+1 during t): P0:{b0,b1} P1:{b2,b3} P2:{a0,a2} P3:{a1,a3}.
// Waits (r2's proven ledger): end-P1 vmcnt(4) drains prev s4={a1,a3} before P2 reads m23;
// end-P3 vmcnt(2) drains s1-s3(next), keeps s4(next). Never 0 in steady state.
#define BM 256
#define BN 256
#define BKB 128

__device__ __forceinline__ i32x16 mfma32(i32x4 a, i32x4 b, i32x16 c) {
    return __builtin_amdgcn_mfma_i32_32x32x32_i8(a, b, c, 0, 0, 0);
}
__device__ __forceinline__ i32x4 ldsld(const int8_t* p) {
    return *reinterpret_cast<const i32x4*>(p);
}
#define FENCE asm volatile("" ::: "memory")
#define BAR   do { FENCE; __builtin_amdgcn_s_barrier(); FENCE; } while (0)
#define LGKM0 asm volatile("s_waitcnt lgkmcnt(0)" ::: "memory")
#define SCHB  __builtin_amdgcn_sched_barrier(0)

template<bool ST>
__device__ __forceinline__ void tile_fn(
    const int8_t* __restrict__ aB, const int8_t* __restrict__ bB,  // per-thread row bases (cur buf)
    int kc0, int kc1, int kc2, int kc3,                            // per-thread k-slot byte offsets
    i32x16 (&acc)[4][2],
    const int8_t* __restrict__ gA, const int8_t* __restrict__ gB,  // per-thread stage src (next tile)
    int8_t* lAn, int8_t* lBn,                                      // next-buf LDS bases
    size_t r64, size_t r128, int t16)
{
    // ================= P0: ks{0,1} x m{0,1} =================
    if (ST) {                                   // stage s1 = {b0,b1}
        G2L16(gB,       lBn + t16);
        G2L16(gB + r64, lBn + 8192 + t16);
    }
    i32x4 A00 = ldsld(aB + 0*4096 + kc0);
    i32x4 A01 = ldsld(aB + 0*4096 + kc1);
    i32x4 A10 = ldsld(aB + 1*4096 + kc0);
    i32x4 A11 = ldsld(aB + 1*4096 + kc1);
    i32x4 B00 = ldsld(bB + 0*4096 + kc0);
    i32x4 B01 = ldsld(bB + 0*4096 + kc1);
    i32x4 B10 = ldsld(bB + 1*4096 + kc0);
    i32x4 B11 = ldsld(bB + 1*4096 + kc1);
    BAR; LGKM0; SCHB;
    __builtin_amdgcn_s_setprio(1);
    acc[0][0] = mfma32(A00, B00, acc[0][0]);
    acc[1][0] = mfma32(A10, B00, acc[1][0]);
    acc[0][1] = mfma32(A00, B10, acc[0][1]);
    acc[1][1] = mfma32(A10, B10, acc[1][1]);
    acc[0][0] = mfma32(A01, B01, acc[0][0]);
    acc[1][0] = mfma32(A11, B01, acc[1][0]);
    acc[0][1] = mfma32(A01, B11, acc[0][1]);
    acc[1][1] = mfma32(A11, B11, acc[1][1]);
    __builtin_amdgcn_s_setprio(0);
    BAR;
    // ================= P1: ks{2,3} x m{0,1} =================
    if (ST) {                                   // stage s2 = {b2,b3}
        G2L16(gB + 2*r64, lBn + 16384 + t16);
        G2L16(gB + 3*r64, lBn + 24576 + t16);
    }
    i32x4 A02 = ldsld(aB + 0*4096 + kc2);
    i32x4 A03 = ldsld(aB + 0*4096 + kc3);
    i32x4 A12 = ldsld(aB + 1*4096 + kc2);
    i32x4 A13 = ldsld(aB + 1*4096 + kc3);
    i32x4 B02 = ldsld(bB + 0*4096 + kc2);
    i32x4 B03 = ldsld(bB + 0*4096 + kc3);
    i32x4 B12 = ldsld(bB + 1*4096 + kc2);
    i32x4 B13 = ldsld(bB + 1*4096 + kc3);
    BAR; LGKM0; SCHB;
    __builtin_amdgcn_s_setprio(1);
    acc[0][0] = mfma32(A02, B02, acc[0][0]);
    acc[1][0] = mfma32(A12, B02, acc[1][0]);
    acc[0][1] = mfma32(A02, B12, acc[0][1]);
    acc[1][1] = mfma32(A12, B12, acc[1][1]);
    acc[0][0] = mfma32(A03, B03, acc[0][0]);
    acc[1][0] = mfma32(A13, B03, acc[1][0]);
    acc[0][1] = mfma32(A03, B13, acc[0][1]);
    acc[1][1] = mfma32(A13, B13, acc[1][1]);
    __builtin_amdgcn_s_setprio(0);
    // drain prev tile's s4={a1,a3} of CURRENT buf (all waves, then barrier)
    if (ST) asm volatile("s_waitcnt vmcnt(4)" ::: "memory");
    else    asm volatile("s_waitcnt vmcnt(0)" ::: "memory");
    BAR;
    // ================= P2: ks{0,1} x m{2,3} (B ks01 frags reused) =================
    if (ST) {                                   // stage s3 = {a0,a2}
        G2L16(gA,        lAn + t16);
        G2L16(gA + r128, lAn + 16384 + t16);
    }
    i32x4 A20 = ldsld(aB + 2*4096 + kc0);
    i32x4 A21 = ldsld(aB + 2*4096 + kc1);
    i32x4 A30 = ldsld(aB + 3*4096 + kc0);
    i32x4 A31 = ldsld(aB + 3*4096 + kc1);
    BAR; LGKM0; SCHB;
    __builtin_amdgcn_s_setprio(1);
    acc[2][0] = mfma32(A20, B00, acc[2][0]);
    acc[3][0] = mfma32(A30, B00, acc[3][0]);
    acc[2][1] = mfma32(A20, B10, acc[2][1]);
    acc[3][1] = mfma32(A30, B10, acc[3][1]);
    acc[2][0] = mfma32(A21, B01, acc[2][0]);
    acc[3][0] = mfma32(A31, B01, acc[3][0]);
    acc[2][1] = mfma32(A21, B11, acc[2][1]);
    acc[3][1] = mfma32(A31, B11, acc[3][1]);
    __builtin_amdgcn_s_setprio(0);
    BAR;
    // ================= P3: ks{2,3} x m{2,3} (B ks23 frags reused) =================
    if (ST) {                                   // stage s4 = {a1,a3}
        G2L16(gA + r64,        lAn + 8192  + t16);
        G2L16(gA + r128 + r64, lAn + 24576 + t16);
    }
    i32x4 A22 = ldsld(aB + 2*4096 + kc2);
    i32x4 A23 = ldsld(aB + 2*4096 + kc3);
    i32x4 A32 = ldsld(aB + 3*4096 + kc2);
    i32x4 A33 = ldsld(aB + 3*4096 + kc3);
    BAR; LGKM0; SCHB;
    __builtin_amdgcn_s_setprio(1);
    acc[2][0] = mfma32(A22, B02, acc[2][0]);
    acc[3][0] = mfma32(A32, B02, acc[3][0]);
    acc[2][1] = mfma32(A22, B12, acc[2][1]);
    acc[3][1] = mfma32(A32, B12, acc[3][1]);
    acc[2][0] = mfma32(A23, B03, acc[2][0]);
    acc[3][0] = mfma32(A33, B03, acc[3][0]);
    acc[2][1] = mfma32(A23, B13, acc[2][1]);
    acc[3][1] = mfma32(A33, B13, acc[3][1]);
    __builtin_amdgcn_s_setprio(0);
    if (ST) asm volatile("s_waitcnt vmcnt(2)" ::: "memory");  // drain s1-s3(next); keep s4(next)
    else    asm volatile("s_waitcnt vmcnt(0)" ::: "memory");
    BAR;
}

__global__ __launch_bounds__(512, 2)
void gemm_i8_k(const int8_t* __restrict__ A,    // [M][K]
               const int8_t* __restrict__ B,    // [N][K]
               const float*  __restrict__ sx,   // [M]
               const float*  __restrict__ sw,   // [N]
               const float*  __restrict__ bias, // [N]
               float* __restrict__ C,           // [M][N]
               int M, int N, int K)
{
    __shared__ int8_t lA[2][BM * BKB];   // 2 x 32 KiB, row-major [256][128] XOR-swizzled
    __shared__ int8_t lB[2][BN * BKB];

    const int t    = threadIdx.x;
    const int lane = t & 63;
    const int wid  = t >> 6;
    const int wm   = wid >> 2;   // 0..1
    const int wn   = wid & 3;    // 0..3

    const int nwg = (int)gridDim.x;
    const int bid = (int)blockIdx.x;
    const int swz = ((nwg & 7) == 0) ? ((bid & 7) * (nwg >> 3) + (bid >> 3)) : bid;
    const int nbn = N / BN;
    const int bm  = swz / nbn;
    const int bn  = swz % nbn;

    // fragment-read addressing (32x32 frags, r11-validated layout):
    // row = base + tile*32 + (lane&31); LDS chunk = (2*ks + hi) ^ (lane&7)
    const int r31 = lane & 31;
    const int hi  = lane >> 5;
    const int sw8 = lane & 7;
    const int kc0 = ((0 + hi) ^ sw8) << 4;
    const int kc1 = ((2 + hi) ^ sw8) << 4;
    const int kc2 = ((4 + hi) ^ sw8) << 4;
    const int kc3 = ((6 + hi) ^ sw8) << 4;
    const int aOff = (wm * 128 + r31) * BKB;
    const int bOff = (wn * 64 + r31) * BKB;
    const int8_t* aB0 = &lA[0][aOff];
    const int8_t* aB1 = &lA[1][aOff];
    const int8_t* bB0 = &lB[0][bOff];
    const int8_t* bB1 = &lB[1][bOff];

    // staging (r2 verbatim): thread t covers row (t>>3) of each 64-row slab,
    // source chunk ((t&7) ^ (row&7)); linear LDS dest.
    const int srow = t >> 3;                          // 0..63
    const int skc  = ((t & 7) ^ (srow & 7)) * 16;
    const int t16  = t * 16;
    const int8_t* pA = A + (size_t)(bm * BM + srow) * K + skc;
    const int8_t* pB = B + (size_t)(bn * BN + srow) * K + skc;
    const size_t r64  = (size_t)64  * K;
    const size_t r128 = (size_t)128 * K;

    // prologue: stage K-tile 0 into buffer 0, order s1,s2,s3,s4
    G2L16(pB,              &lB[0][0]     + t16);   // b0
    G2L16(pB + r64,        &lB[0][8192]  + t16);   // b1
    G2L16(pB + 2*r64,      &lB[0][16384] + t16);   // b2
    G2L16(pB + 3*r64,      &lB[0][24576] + t16);   // b3
    G2L16(pA,              &lA[0][0]     + t16);   // a0
    G2L16(pA + r128,       &lA[0][16384] + t16);   // a2
    G2L16(pA + r64,        &lA[0][8192]  + t16);   // a1
    G2L16(pA + r128 + r64, &lA[0][24576] + t16);   // a3
    asm volatile("s_waitcnt vmcnt(2)" ::: "memory");   // s1-s3 resident; s4={a1,a3} in flight
    BAR;

    i32x16 acc[4][2] = {};

    const int NT = K / BKB;   // 32 (even)
    for (int tt = 0; tt + 2 < NT; tt += 2) {
        const size_t ko1 = (size_t)(tt + 1) * BKB;
        tile_fn<true>(aB0, bB0, kc0, kc1, kc2, kc3, acc, pA + ko1, pB + ko1, &lA[1][0], &lB[1][0], r64, r128, t16);
        const size_t ko2 = (size_t)(tt + 2) * BKB;
        tile_fn<true>(aB1, bB1, kc0, kc1, kc2, kc3, acc, pA + ko2, pB + ko2, &lA[0][0], &lB[0][0], r64, r128, t16);
    }
    {   // last two tiles: NT-2 (stages NT-1), then NT-1 (no stage)
        const size_t ko1 = (size_t)(NT - 1) * BKB;
        tile_fn<true >(aB0, bB0, kc0, kc1, kc2, kc3, acc, pA + ko1, pB + ko1, &lA[1][0], &lB[1][0], r64, r128, t16);
        tile_fn<false>(aB1, bB1, kc0, kc1, kc2, kc3, acc, pA, pB, &lA[0][0], &lB[0][0], r64, r128, t16);
    }

    // epilogue: dequant + bias (32x32 C/D layout, r11-validated)
    const int col0 = bn * BN + wn * 64 + r31;
    #pragma unroll
    for (int ni = 0; ni < 2; ++ni) {
        const int c = col0 + ni * 32;
        const float swc = sw[c];
        const float bc  = bias[c];
        #pragma unroll
        for (int mi = 0; mi < 4; ++mi) {
            const int rb = bm * BM + wm * 128 + mi * 32 + 4 * hi;
            #pragma unroll
            for (int r = 0; r < 16; ++r) {
                const int row = rb + (r & 3) + 8 * (r >> 2);
                C[(size_t)row * N + c] = (float)acc[mi][ni][r] * sx[row] * swc + bc;
            }
        }
    }
}

extern "C" void kernel_launch(void* const* d_in, const int* in_sizes, int n_in,
                              void* d_out, int out_size, void* d_ws, size_t ws_size,
                              hipStream_t stream) {
    const float* x    = (const float*)d_in[0];
    const float* w    = (const float*)d_in[1];
    const float* bias = (const float*)d_in[2];
    float* out = (float*)d_out;

    const int dout   = in_sizes[2];          // 16384
    const int din    = in_sizes[1] / dout;   // 4096
    const int tokens = in_sizes[0] / din;    // 4096

    char* ws = (char*)d_ws;
    float*  sx = (float*)ws;
    float*  sw = (float*)(ws + 16384);
    int8_t* xq = (int8_t*)(ws + 16384 + 65536);
    int8_t* wq = xq + (size_t)tokens * din;

    quant_rows_k<4096><<<tokens, 256, 0, stream>>>(x, xq, sx);
    quant_rows_k<4096><<<dout,   256, 0, stream>>>(w, wq, sw);

    const int grid = (tokens / BM) * (dout / BN);   // 16 * 64 = 1024
    gemm_i8_k<<<grid, 512, 0, stream>>>(xq, wq, sx, sw, bias, out, tokens, dout, din);
}